// Round 1
// baseline (2275.587 us; speedup 1.0000x reference)
//
#include <hip/hip_runtime.h>

#define D 128
#define NPB 32  // nodes per MLP block

// ---------------- scatter: agg[recv[e]] += edge_attr[e] ----------------
__global__ __launch_bounds__(256) void scatter_kernel(
    const float* __restrict__ edge_attr,
    const int* __restrict__ recv,
    float* __restrict__ agg,
    int n_edges)
{
    int idx = blockIdx.x * 256 + threadIdx.x;   // one thread = 4 floats
    int e = idx >> 5;                            // 32 threads per edge
    if (e >= n_edges) return;
    int r4 = (idx & 31) * 4;
    const float4 v = *(const float4*)(edge_attr + (size_t)e * D + r4);
    int node = recv[e];
    float* dst = agg + (size_t)node * D + r4;
    atomicAdd(dst + 0, v.x);
    atomicAdd(dst + 1, v.y);
    atomicAdd(dst + 2, v.z);
    atomicAdd(dst + 3, v.w);
}

// ---------------- fused MLP: out = relu([x|agg] @ W1 + b1) @ W2 + b2 ----------------
__global__ __launch_bounds__(256) void mlp_kernel(
    const float* __restrict__ x,
    const float* __restrict__ agg,
    const float* __restrict__ W1,   // [2D, D]
    const float* __restrict__ b1,   // [D]
    const float* __restrict__ W2,   // [D, D]
    const float* __restrict__ b2,   // [D]
    float* __restrict__ out,        // [N, D]
    int n_nodes)
{
    __shared__ float in_s[NPB][2 * D];  // 32 KB
    __shared__ float h_s[NPB][D];       // 16 KB

    const int t = threadIdx.x;
    const int node0 = blockIdx.x * NPB;

    // ---- stage x|agg into LDS: NPB*64 float4s, 256 threads -> 8 each ----
    for (int i = t; i < NPB * 64; i += 256) {
        int m  = i >> 6;       // node within block
        int c4 = i & 63;       // float4 index within 2D row
        int node = node0 + m;
        float4 v = make_float4(0.f, 0.f, 0.f, 0.f);
        if (node < n_nodes) {
            if (c4 < 32) v = *(const float4*)(x   + (size_t)node * D + c4 * 4);
            else         v = *(const float4*)(agg + (size_t)node * D + (c4 - 32) * 4);
        }
        *(float4*)(&in_s[m][c4 * 4]) = v;
    }
    __syncthreads();

    // thread -> (2 cols, 8 nodes)
    const int cg = t & 63;        // cols cg and cg+64
    const int ng = t >> 6;        // node group: nodes ng*8 .. ng*8+7
    const int j0 = cg, j1 = cg + 64;
    const int m0 = ng * 8;

    // ---- layer 1 ----
    float acc0[8], acc1[8];
    {
        const float bb0 = b1[j0], bb1 = b1[j1];
#pragma unroll
        for (int m = 0; m < 8; ++m) { acc0[m] = bb0; acc1[m] = bb1; }
    }
    for (int k = 0; k < 2 * D; k += 4) {
        float w0[4], w1[4];
#pragma unroll
        for (int r = 0; r < 4; ++r) {
            w0[r] = W1[(k + r) * D + j0];
            w1[r] = W1[(k + r) * D + j1];
        }
#pragma unroll
        for (int m = 0; m < 8; ++m) {
            const float4 v = *(const float4*)(&in_s[m0 + m][k]);
            acc0[m] += v.x * w0[0] + v.y * w0[1] + v.z * w0[2] + v.w * w0[3];
            acc1[m] += v.x * w1[0] + v.y * w1[1] + v.z * w1[2] + v.w * w1[3];
        }
    }
#pragma unroll
    for (int m = 0; m < 8; ++m) {
        h_s[m0 + m][j0] = fmaxf(acc0[m], 0.f);
        h_s[m0 + m][j1] = fmaxf(acc1[m], 0.f);
    }
    __syncthreads();

    // ---- layer 2 ----
    float o0[8], o1[8];
    {
        const float bb0 = b2[j0], bb1 = b2[j1];
#pragma unroll
        for (int m = 0; m < 8; ++m) { o0[m] = bb0; o1[m] = bb1; }
    }
    for (int j = 0; j < D; j += 4) {
        float w0[4], w1[4];
#pragma unroll
        for (int r = 0; r < 4; ++r) {
            w0[r] = W2[(j + r) * D + j0];
            w1[r] = W2[(j + r) * D + j1];
        }
#pragma unroll
        for (int m = 0; m < 8; ++m) {
            const float4 v = *(const float4*)(&h_s[m0 + m][j]);
            o0[m] += v.x * w0[0] + v.y * w0[1] + v.z * w0[2] + v.w * w0[3];
            o1[m] += v.x * w1[0] + v.y * w1[1] + v.z * w1[2] + v.w * w1[3];
        }
    }

    // ---- store ----
#pragma unroll
    for (int m = 0; m < 8; ++m) {
        int node = node0 + m0 + m;
        if (node < n_nodes) {
            out[(size_t)node * D + j0] = o0[m];
            out[(size_t)node * D + j1] = o1[m];
        }
    }
}

extern "C" void kernel_launch(void* const* d_in, const int* in_sizes, int n_in,
                              void* d_out, int out_size, void* d_ws, size_t ws_size,
                              hipStream_t stream) {
    const float* x         = (const float*)d_in[0];
    const float* edge_attr = (const float*)d_in[1];
    const int*   edge_index= (const int*)d_in[2];
    const float* W1        = (const float*)d_in[3];
    const float* b1        = (const float*)d_in[4];
    const float* W2        = (const float*)d_in[5];
    const float* b2        = (const float*)d_in[6];
    float* out = (float*)d_out;

    const int n_nodes = in_sizes[0] / D;       // 200000
    const int n_edges = in_sizes[1] / D;       // 800000
    const int* recv = edge_index + n_edges;    // row 1 of [2, E]

    float* agg = (float*)d_ws;                 // [N, D] scratch

    hipMemsetAsync(agg, 0, (size_t)n_nodes * D * sizeof(float), stream);

    {
        int total = n_edges * 32;              // threads (4 floats each)
        int blocks = (total + 255) / 256;
        scatter_kernel<<<blocks, 256, 0, stream>>>(edge_attr, recv, agg, n_edges);
    }
    {
        int blocks = (n_nodes + NPB - 1) / NPB;  // 6250
        mlp_kernel<<<blocks, 256, 0, stream>>>(x, agg, W1, b1, W2, b2, out, n_nodes);
    }
}

// Round 2
// 760.761 us; speedup vs baseline: 2.9912x; 2.9912x over previous
//
#include <hip/hip_runtime.h>

#define D 128
#define NPB 32  // nodes per MLP block

typedef __attribute__((ext_vector_type(8))) short short8;
typedef __attribute__((ext_vector_type(4))) float f32x4;

__device__ inline unsigned short f2bf(float f) {
    unsigned int u = __float_as_uint(f);
    u += 0x7fffu + ((u >> 16) & 1u);   // round-to-nearest-even
    return (unsigned short)(u >> 16);
}

// ---- pack W1 [2D,D] and W2 [D,D] into MFMA B-fragment order, bf16 ----
// B-frag for (col-tile c, k-step s): lane l holds B[k][n], n = c*16 + (l&15),
// k = s*32 + (l>>4)*8 + j, j=0..7 contiguous -> one 16B load per fragment.
__global__ __launch_bounds__(256) void pack_weights_kernel(
    const float* __restrict__ W1, const float* __restrict__ W2,
    unsigned short* __restrict__ pW1, unsigned short* __restrict__ pW2)
{
    int idx = blockIdx.x * 256 + threadIdx.x;
    if (idx < 32768) {            // 8 c-tiles * 8 s-steps * 64 lanes * 8
        int j = idx & 7, lane = (idx >> 3) & 63, s = (idx >> 9) & 7, c = idx >> 12;
        int k = s * 32 + ((lane >> 4) << 3) + j;
        int n = (c << 4) + (lane & 15);
        pW1[idx] = f2bf(W1[k * D + n]);
    } else if (idx < 49152) {     // 8 c-tiles * 4 s-steps * 64 lanes * 8
        int i2 = idx - 32768;
        int j = i2 & 7, lane = (i2 >> 3) & 63, s = (i2 >> 9) & 3, c = i2 >> 11;
        int k = s * 32 + ((lane >> 4) << 3) + j;
        int n = (c << 4) + (lane & 15);
        pW2[i2] = f2bf(W2[k * D + n]);
    }
}

// ---- CSR build: histogram -> scan -> reorder ----
__global__ __launch_bounds__(256) void hist_kernel(
    const int* __restrict__ recv, int* __restrict__ counts, int n_edges)
{
    int e = blockIdx.x * 256 + threadIdx.x;
    if (e < n_edges) atomicAdd(&counts[recv[e]], 1);
}

__global__ __launch_bounds__(256) void reduce_kernel(
    const int* __restrict__ counts, int* __restrict__ blocksum, int n)
{
    __shared__ int s[256];
    int t = threadIdx.x, i = blockIdx.x * 256 + t;
    s[t] = (i < n) ? counts[i] : 0;
    __syncthreads();
    for (int off = 128; off > 0; off >>= 1) {
        if (t < off) s[t] += s[t + off];
        __syncthreads();
    }
    if (t == 0) blocksum[blockIdx.x] = s[0];
}

__global__ __launch_bounds__(1024) void scanblk_kernel(
    const int* __restrict__ blocksum, int* __restrict__ blockoff, int nblocks)
{
    __shared__ int s[1024];
    int t = threadIdx.x;
    int v = (t < nblocks) ? blocksum[t] : 0;
    s[t] = v;
    __syncthreads();
    for (int off = 1; off < 1024; off <<= 1) {
        int add = (t >= off) ? s[t - off] : 0;
        __syncthreads();
        s[t] += add;
        __syncthreads();
    }
    if (t < nblocks) blockoff[t] = s[t] - v;   // exclusive
}

__global__ __launch_bounds__(256) void scan_kernel(
    const int* __restrict__ counts, const int* __restrict__ blockoff,
    int* __restrict__ starts, int* __restrict__ cursor, int n)
{
    __shared__ int s[256];
    int t = threadIdx.x, i = blockIdx.x * 256 + t;
    int v = (i < n) ? counts[i] : 0;
    s[t] = v;
    __syncthreads();
    for (int off = 1; off < 256; off <<= 1) {
        int add = (t >= off) ? s[t - off] : 0;
        __syncthreads();
        s[t] += add;
        __syncthreads();
    }
    int excl = s[t] - v + blockoff[blockIdx.x];
    if (i < n) {
        starts[i] = excl;
        cursor[i] = excl;
        if (i == n - 1) starts[n] = excl + v;
    }
}

__global__ __launch_bounds__(256) void reorder_kernel(
    const int* __restrict__ recv, int* __restrict__ cursor,
    int* __restrict__ edge_ids, int n_edges)
{
    int e = blockIdx.x * 256 + threadIdx.x;
    if (e < n_edges) {
        int r = recv[e];
        int pos = atomicAdd(&cursor[r], 1);
        edge_ids[pos] = e;
    }
}

// ---- fused gather + MLP (bf16 MFMA, fp32 accumulate) ----
__global__ __launch_bounds__(256) void mlp_kernel(
    const float* __restrict__ x, const float* __restrict__ edge_attr,
    const int* __restrict__ starts, const int* __restrict__ edge_ids,
    const unsigned short* __restrict__ pW1, const unsigned short* __restrict__ pW2,
    const float* __restrict__ b1, const float* __restrict__ b2,
    float* __restrict__ out, int n_nodes)
{
    __shared__ unsigned short in_s[NPB][2 * D + 8];  // +8 bf16 pad -> 2-way LDS aliasing (free)
    __shared__ unsigned short h_s[NPB][D + 8];

    const int t = threadIdx.x;
    const int node0 = blockIdx.x * NPB;

    // stage x rows as bf16
    for (int i = t; i < NPB * 32; i += 256) {
        int m = i >> 5, c4 = i & 31;
        int node = node0 + m;
        float4 v = make_float4(0.f, 0.f, 0.f, 0.f);
        if (node < n_nodes) v = *(const float4*)(x + (size_t)node * D + c4 * 4);
        ushort4 b;
        b.x = f2bf(v.x); b.y = f2bf(v.y); b.z = f2bf(v.z); b.w = f2bf(v.w);
        *(ushort4*)(&in_s[m][c4 * 4]) = b;
    }

    // gather edge sums: half-wave (32 lanes) per node, 4 nodes per group
    {
        int g = t >> 5, l32 = t & 31;
        for (int i = 0; i < 4; ++i) {
            int m = g * 4 + i;
            int node = node0 + m;
            float4 acc = make_float4(0.f, 0.f, 0.f, 0.f);
            if (node < n_nodes) {
                int p = starts[node], pe = starts[node + 1];
                for (; p + 1 < pe; p += 2) {
                    int e0 = edge_ids[p], e1 = edge_ids[p + 1];
                    float4 v0 = *(const float4*)(edge_attr + (size_t)e0 * D + l32 * 4);
                    float4 v1 = *(const float4*)(edge_attr + (size_t)e1 * D + l32 * 4);
                    acc.x += v0.x + v1.x; acc.y += v0.y + v1.y;
                    acc.z += v0.z + v1.z; acc.w += v0.w + v1.w;
                }
                if (p < pe) {
                    int e0 = edge_ids[p];
                    float4 v0 = *(const float4*)(edge_attr + (size_t)e0 * D + l32 * 4);
                    acc.x += v0.x; acc.y += v0.y; acc.z += v0.z; acc.w += v0.w;
                }
            }
            ushort4 b;
            b.x = f2bf(acc.x); b.y = f2bf(acc.y); b.z = f2bf(acc.z); b.w = f2bf(acc.w);
            *(ushort4*)(&in_s[m][D + l32 * 4]) = b;
        }
    }
    __syncthreads();

    const int w = t >> 6, l = t & 63;
    const int col = l & 15, quad = l >> 4;
    const int c0 = w * 2, c1 = c0 + 1;

    // ---- layer 1: [32 x 256] @ [256 x 128], wave w owns col-tiles c0,c1 ----
    f32x4 a00, a01, a10, a11;
    {
        float bA = b1[c0 * 16 + col], bB = b1[c1 * 16 + col];
        a00 = (f32x4){bA, bA, bA, bA}; a01 = (f32x4){bB, bB, bB, bB};
        a10 = a00; a11 = a01;
    }
#pragma unroll
    for (int s = 0; s < 8; ++s) {
        short8 fa0 = *(const short8*)(&in_s[col][s * 32 + quad * 8]);
        short8 fa1 = *(const short8*)(&in_s[16 + col][s * 32 + quad * 8]);
        short8 fb0 = *(const short8*)(pW1 + (((c0 * 8 + s) * 64 + l) * 8));
        short8 fb1 = *(const short8*)(pW1 + (((c1 * 8 + s) * 64 + l) * 8));
        a00 = __builtin_amdgcn_mfma_f32_16x16x32_bf16(fa0, fb0, a00, 0, 0, 0);
        a01 = __builtin_amdgcn_mfma_f32_16x16x32_bf16(fa0, fb1, a01, 0, 0, 0);
        a10 = __builtin_amdgcn_mfma_f32_16x16x32_bf16(fa1, fb0, a10, 0, 0, 0);
        a11 = __builtin_amdgcn_mfma_f32_16x16x32_bf16(fa1, fb1, a11, 0, 0, 0);
    }
#pragma unroll
    for (int r = 0; r < 4; ++r) {
        int row = quad * 4 + r;   // C/D: col = l&15, row = quad*4 + reg
        h_s[row][c0 * 16 + col]      = f2bf(fmaxf(a00[r], 0.f));
        h_s[row][c1 * 16 + col]      = f2bf(fmaxf(a01[r], 0.f));
        h_s[16 + row][c0 * 16 + col] = f2bf(fmaxf(a10[r], 0.f));
        h_s[16 + row][c1 * 16 + col] = f2bf(fmaxf(a11[r], 0.f));
    }
    __syncthreads();

    // ---- layer 2: [32 x 128] @ [128 x 128] ----
    f32x4 o00, o01, o10, o11;
    {
        float bA = b2[c0 * 16 + col], bB = b2[c1 * 16 + col];
        o00 = (f32x4){bA, bA, bA, bA}; o01 = (f32x4){bB, bB, bB, bB};
        o10 = o00; o11 = o01;
    }
#pragma unroll
    for (int s = 0; s < 4; ++s) {
        short8 fa0 = *(const short8*)(&h_s[col][s * 32 + quad * 8]);
        short8 fa1 = *(const short8*)(&h_s[16 + col][s * 32 + quad * 8]);
        short8 fb0 = *(const short8*)(pW2 + (((c0 * 4 + s) * 64 + l) * 8));
        short8 fb1 = *(const short8*)(pW2 + (((c1 * 4 + s) * 64 + l) * 8));
        o00 = __builtin_amdgcn_mfma_f32_16x16x32_bf16(fa0, fb0, o00, 0, 0, 0);
        o01 = __builtin_amdgcn_mfma_f32_16x16x32_bf16(fa0, fb1, o01, 0, 0, 0);
        o10 = __builtin_amdgcn_mfma_f32_16x16x32_bf16(fa1, fb0, o10, 0, 0, 0);
        o11 = __builtin_amdgcn_mfma_f32_16x16x32_bf16(fa1, fb1, o11, 0, 0, 0);
    }
#pragma unroll
    for (int r = 0; r < 4; ++r) {
        int row = quad * 4 + r;
        int na = node0 + row, nb = node0 + 16 + row;
        if (na < n_nodes) {
            out[(size_t)na * D + c0 * 16 + col] = o00[r];
            out[(size_t)na * D + c1 * 16 + col] = o01[r];
        }
        if (nb < n_nodes) {
            out[(size_t)nb * D + c0 * 16 + col] = o10[r];
            out[(size_t)nb * D + c1 * 16 + col] = o11[r];
        }
    }
}

extern "C" void kernel_launch(void* const* d_in, const int* in_sizes, int n_in,
                              void* d_out, int out_size, void* d_ws, size_t ws_size,
                              hipStream_t stream) {
    const float* x         = (const float*)d_in[0];
    const float* edge_attr = (const float*)d_in[1];
    const int*   edge_index= (const int*)d_in[2];
    const float* W1        = (const float*)d_in[3];
    const float* b1        = (const float*)d_in[4];
    const float* W2        = (const float*)d_in[5];
    const float* b2        = (const float*)d_in[6];
    float* out = (float*)d_out;

    const int n_nodes = in_sizes[0] / D;       // 200000
    const int n_edges = in_sizes[1] / D;       // 800000
    const int* recv = edge_index + n_edges;    // row 1 of [2, E]

    char* wsb = (char*)d_ws;
    int* counts   = (int*)(wsb + 0);                         // 800 KB
    int* cursor   = (int*)(wsb + (1u << 20));                // 800 KB
    int* starts   = (int*)(wsb + (2u << 20));                // 800 KB + 4
    int* blocksum = (int*)(wsb + (3u << 20));                // 4 KB
    int* blockoff = (int*)(wsb + (3u << 20) + (1u << 16));   // 4 KB
    int* edge_ids = (int*)(wsb + (4u << 20));                // 3.2 MB
    unsigned short* pW1 = (unsigned short*)(wsb + (8u << 20));              // 64 KB
    unsigned short* pW2 = (unsigned short*)(wsb + (8u << 20) + (1u << 17)); // 32 KB

    hipMemsetAsync(counts, 0, (size_t)n_nodes * sizeof(int), stream);

    pack_weights_kernel<<<192, 256, 0, stream>>>(W1, W2, pW1, pW2);

    const int eb = (n_edges + 255) / 256;
    hist_kernel<<<eb, 256, 0, stream>>>(recv, counts, n_edges);

    const int nb = (n_nodes + 255) / 256;      // 782 (<= 1024 for scanblk)
    reduce_kernel<<<nb, 256, 0, stream>>>(counts, blocksum, n_nodes);
    scanblk_kernel<<<1, 1024, 0, stream>>>(blocksum, blockoff, nb);
    scan_kernel<<<nb, 256, 0, stream>>>(counts, blockoff, starts, cursor, n_nodes);
    reorder_kernel<<<eb, 256, 0, stream>>>(recv, cursor, edge_ids, n_edges);

    mlp_kernel<<<(n_nodes + NPB - 1) / NPB, 256, 0, stream>>>(
        x, edge_attr, starts, edge_ids, pW1, pW2, b1, b2, out, n_nodes);
}